// Round 1
// baseline (251.618 us; speedup 1.0000x reference)
//
#include <hip/hip_runtime.h>
#include <math.h>

// S4D forward (conv mode) via chunked linear recurrence, loop order n-outer.
// y[b,l,d] = D[d]*x[b,l,d] + sum_n CB[d,n] * h_n[l],  h_n[l] = a_n h_n[l-1] + x[l]
// a = exp(dt*A), CB = C * expm1(dt*A)/A * B, A_n = -0.5*(n+1)
//
// This revision: chunk length T is a template parameter. T=32 halves the
// per-thread register arrays (xv[T]+acc[T]) so the out/state kernels stop
// overflowing into AGPRs (prev: 76 arch VGPR + ~128 AGPR -> 2 waves/SIMD,
// 23% occupancy, VALUBusy 54%). T=32 needs a 135 MB workspace (u-array
// doubles); ws_size is checked at runtime with a T=64 fallback.

namespace {
constexpr int kBatch = 8;
constexpr int kLen   = 2048;
constexpr int kD     = 1024;
constexpr int kN     = 64;   // states

template <int T>
struct Cfg {
  static constexpr int  kC     = kLen / T;                     // chunks
  static constexpr long kU     = (long)kBatch * kC * kN * kD;  // u/s region
  static constexpr long kAOff  = kU;                           // a[n][d]
  static constexpr long kCbOff = kAOff + (long)kN * kD;        // cb[n][d]
  static constexpr long kAtOff = kCbOff + (long)kN * kD;       // a^T[n][d]
  static constexpr long kBytes = (kAtOff + (long)kN * kD) * 4;
};
// T=32: kBytes = 135,004,160 (~128.8 MiB).  T=64: 67,895,296 (~64.8 MiB).
}  // namespace

template <int T>
__global__ void s4d_coef_kernel(const float* __restrict__ log_dt,
                                const float* __restrict__ Bm,
                                const float* __restrict__ Cm,
                                float* __restrict__ ws) {
  int tid = blockIdx.x * blockDim.x + threadIdx.x;  // 65536 threads
  int d = tid & (kD - 1);
  int n = tid >> 10;
  float dt  = expf(log_dt[d]);
  float An  = -0.5f * (float)(n + 1);
  float dtA = dt * An;
  float a   = expf(dtA);
  float bbar = (expm1f(dtA) / An) * Bm[d * kN + n];
  float cb   = Cm[d * kN + n] * bbar;
  float aT   = expf(dtA * (float)T);  // a^T
  ws[Cfg<T>::kAOff  + (long)n * kD + d] = a;
  ws[Cfg<T>::kCbOff + (long)n * kD + d] = cb;
  ws[Cfg<T>::kAtOff + (long)n * kD + d] = aT;
}

// Phase 1: chunk-local end states only (zero initial state).
template <int T>
__global__ __launch_bounds__(256, T == 32 ? 8 : 4) void s4d_state_kernel(
    const float* __restrict__ x, float* __restrict__ ws) {
  constexpr int C = Cfg<T>::kC;
  int tid = blockIdx.x * blockDim.x + threadIdx.x;  // kBatch*C*kD threads
  int d  = tid & (kD - 1);   // consecutive lanes -> consecutive d: coalesced
  int bc = tid >> 10;
  int b  = bc / C;
  int c  = bc % C;

  const float* xp = x + ((long)b * kLen + (long)c * T) * kD + d;
  float xv[T];
#pragma unroll
  for (int t = 0; t < T; ++t) xv[t] = xp[(long)t * kD];

  const float* ap = ws + Cfg<T>::kAOff + d;
  float* up = ws + ((long)(b * C + c) * kN) * kD + d;
#pragma unroll 4
  for (int n = 0; n < kN; ++n) {
    float a = ap[(long)n * kD];
    float h = 0.f;
#pragma unroll
    for (int t = 0; t < T; ++t) h = fmaf(h, a, xv[t]);
    up[(long)n * kD] = h;
  }
}

// Phase 2: inter-chunk scan. After this, ws[u-region] holds s_start[c] =
// state at the END of chunk c-1 (i.e. initial state for chunk c).
template <int T>
__global__ void s4d_scan_kernel(float* __restrict__ ws) {
  constexpr int C = Cfg<T>::kC;
  int tid = blockIdx.x * blockDim.x + threadIdx.x;  // kBatch*kN*kD threads
  int d  = tid & (kD - 1);
  int bn = tid >> 10;
  int n  = bn & (kN - 1);
  int b  = bn >> 6;
  float aT = ws[Cfg<T>::kAtOff + (long)n * kD + d];
  float* up = ws + ((long)b * C * kN + n) * kD + d;
  const long cstride = (long)kN * kD;
  float s = 0.f;
#pragma unroll 1
  for (int c = 0; c < C; ++c) {
    float u = up[(long)c * cstride];
    up[(long)c * cstride] = s;  // in place: u[c] -> s_start[c]
    s = fmaf(aT, s, u);
  }
}

// Phase 3: full output. Recurrence with proper initial state, single y write.
// Rotating software prefetch of next-n (a, cb, s): the prefetch at n+1 == kN
// reads the following ws region (tables / next chunk) -- in-bounds garbage,
// never used.
template <int T>
__global__ __launch_bounds__(256, T == 32 ? 5 : 2) void s4d_out_kernel(
    const float* __restrict__ x, const float* __restrict__ Dv,
    float* __restrict__ y, const float* __restrict__ ws) {
  constexpr int C = Cfg<T>::kC;
  int tid = blockIdx.x * blockDim.x + threadIdx.x;  // kBatch*C*kD threads
  int d  = tid & (kD - 1);
  int bc = tid >> 10;
  int b  = bc / C;
  int c  = bc % C;

  const float* xp = x + ((long)b * kLen + (long)c * T) * kD + d;
  float xv[T];
#pragma unroll
  for (int t = 0; t < T; ++t) xv[t] = xp[(long)t * kD];

  float Dd = Dv[d];
  float acc[T];
#pragma unroll
  for (int t = 0; t < T; ++t) acc[t] = Dd * xv[t];

  const float* ap  = ws + Cfg<T>::kAOff + d;
  const float* cbp = ws + Cfg<T>::kCbOff + d;
  const float* sp  = ws + ((long)(b * C + c) * kN) * kD + d;

  float an = ap[0], cbn = cbp[0], hn = sp[0];
#pragma unroll 2
  for (int n = 0; n < kN; ++n) {
    float a2  = ap[(long)(n + 1) * kD];   // prefetch next n
    float cb2 = cbp[(long)(n + 1) * kD];
    float s2  = sp[(long)(n + 1) * kD];
    float a = an, cb = cbn, h = hn;
#pragma unroll
    for (int t = 0; t < T; ++t) {
      h = fmaf(h, a, xv[t]);
      acc[t] = fmaf(cb, h, acc[t]);
    }
    an = a2; cbn = cb2; hn = s2;
  }

  float* yp = y + ((long)b * kLen + (long)c * T) * kD + d;
#pragma unroll
  for (int t = 0; t < T; ++t) yp[(long)t * kD] = acc[t];
}

template <int T>
static void launch_all(const float* x, const float* log_dt, const float* Bm,
                       const float* Cm, const float* Dv, float* y, float* ws,
                       hipStream_t stream) {
  constexpr int C = Cfg<T>::kC;
  hipLaunchKernelGGL((s4d_coef_kernel<T>), dim3((kN * kD) / 256), dim3(256), 0,
                     stream, log_dt, Bm, Cm, ws);
  hipLaunchKernelGGL((s4d_state_kernel<T>), dim3((kBatch * C * kD) / 256),
                     dim3(256), 0, stream, x, ws);
  hipLaunchKernelGGL((s4d_scan_kernel<T>), dim3((kBatch * kN * kD) / 256),
                     dim3(256), 0, stream, ws);
  hipLaunchKernelGGL((s4d_out_kernel<T>), dim3((kBatch * C * kD) / 256),
                     dim3(256), 0, stream, x, Dv, y, ws);
}

extern "C" void kernel_launch(void* const* d_in, const int* in_sizes, int n_in,
                              void* d_out, int out_size, void* d_ws,
                              size_t ws_size, hipStream_t stream) {
  const float* x      = (const float*)d_in[0];
  const float* log_dt = (const float*)d_in[1];
  const float* Bm     = (const float*)d_in[2];
  const float* Cm     = (const float*)d_in[3];
  const float* Dv     = (const float*)d_in[4];
  float* y  = (float*)d_out;
  float* ws = (float*)d_ws;

  if (ws_size >= (size_t)Cfg<32>::kBytes) {
    launch_all<32>(x, log_dt, Bm, Cm, Dv, y, ws, stream);
  } else {
    launch_all<64>(x, log_dt, Bm, Cm, Dv, y, ws, stream);  // safe fallback
  }
}